// Round 1
// baseline (338.511 us; speedup 1.0000x reference)
//
#include <hip/hip_runtime.h>
#include <hip/hip_bf16.h>

typedef __attribute__((ext_vector_type(4))) float  f32x4;
typedef __attribute__((ext_vector_type(8))) short  s16x8;

using bf16 = __hip_bfloat16;

#define DIMC   1024
#define NH     16
#define HD     64
#define SEQ    2048
#define NB     2
#define NROWS  (NB*SEQ)   // 4096
#define NQKV   1152       // 1024 q + 64 k + 64 v

// ---------------- cast fp32 -> bf16 (4 elems/thread) ----------------
__global__ __launch_bounds__(256) void cast_kernel(const float* __restrict__ src,
                                                   bf16* __restrict__ dst, int n4) {
  int i = blockIdx.x * blockDim.x + threadIdx.x;
  if (i < n4) {
    float4 v = ((const float4*)src)[i];
    bf16* d = dst + (size_t)i * 4;
    d[0] = __float2bfloat16(v.x);
    d[1] = __float2bfloat16(v.y);
    d[2] = __float2bfloat16(v.z);
    d[3] = __float2bfloat16(v.w);
  }
}

// ---------------- bf16 GEMM: C[M][N] = A[M][K] * B[N][K]^T  (fp32 out) ----
// 128x128 tile, BK=64, 4 waves (2x2), per-wave 64x64, mfma 16x16x32 bf16.
__global__ __launch_bounds__(256) void gemm_bt(const bf16* __restrict__ A,
                                               const bf16* __restrict__ Bm,
                                               float* __restrict__ C,
                                               int M, int N, int K) {
  __shared__ bf16 lA[128 * 64];
  __shared__ bf16 lB[128 * 64];
  const int tid = threadIdx.x;
  const int w = tid >> 6, l = tid & 63;
  const int lg = l >> 4, ln = l & 15;
  const int wr = w >> 1, wc = w & 1;
  const int m0 = blockIdx.x * 128, n0 = blockIdx.y * 128;

  f32x4 acc[4][4] = {};

  for (int k0 = 0; k0 < K; k0 += 64) {
    // stage A and B tiles (128x64 bf16 each) via 16B vector loads
    for (int c = tid; c < 1024; c += 256) {
      int row = c >> 3, col = (c & 7) * 8;
      *(s16x8*)(&lA[row * 64 + col]) =
          *(const s16x8*)(A + (size_t)(m0 + row) * K + k0 + col);
      *(s16x8*)(&lB[row * 64 + col]) =
          *(const s16x8*)(Bm + (size_t)(n0 + row) * K + k0 + col);
    }
    __syncthreads();
    for (int ks = 0; ks < 2; ++ks) {
      s16x8 af[4], bfr[4];
      for (int m = 0; m < 4; ++m)
        af[m] = *(const s16x8*)(&lA[(wr * 64 + m * 16 + ln) * 64 + ks * 32 + lg * 8]);
      for (int n = 0; n < 4; ++n)
        bfr[n] = *(const s16x8*)(&lB[(wc * 64 + n * 16 + ln) * 64 + ks * 32 + lg * 8]);
      for (int m = 0; m < 4; ++m)
        for (int n = 0; n < 4; ++n)
          acc[m][n] = __builtin_amdgcn_mfma_f32_16x16x32_bf16(af[m], bfr[n], acc[m][n], 0, 0, 0);
    }
    __syncthreads();
  }

  for (int m = 0; m < 4; ++m)
    for (int n = 0; n < 4; ++n)
      for (int r = 0; r < 4; ++r)
        C[(size_t)(m0 + wr * 64 + m * 16 + lg * 4 + r) * N + n0 + wc * 64 + n * 16 + ln] =
            acc[m][n][r];
}

// ---------------- RoPE + layout: Y[4096][1152] fp32 -> Q,K (rotated bf16), Vt ----
__global__ __launch_bounds__(256) void rope_kernel(const float* __restrict__ Y,
                                                   bf16* __restrict__ Qb,
                                                   bf16* __restrict__ Kb,
                                                   bf16* __restrict__ Vt) {
  const int r = blockIdx.x;             // 0..4095
  const int b = r >> 11, s = r & 2047;
  const float* y = Y + (size_t)r * NQKV;
  for (int t = threadIdx.x; t < 576; t += blockDim.x) {
    if (t < 512) {                      // q pairs: h = t/32, i = t%32
      int h = t >> 5, i = t & 31;
      float x1 = y[h * 64 + 2 * i], x2 = y[h * 64 + 2 * i + 1];
      float fr = expf(-(float)i * (9.210340371976184f / 32.0f)); // theta^(-i/32)
      float sn, cs;
      sincosf((float)s * fr, &sn, &cs);
      bf16* q = Qb + ((size_t)((b * NH + h) * SEQ + s)) * HD + 2 * i;
      q[0] = __float2bfloat16(x1 * cs - x2 * sn);
      q[1] = __float2bfloat16(x1 * sn + x2 * cs);
    } else if (t < 544) {               // k pairs
      int i = t - 512;
      float x1 = y[1024 + 2 * i], x2 = y[1024 + 2 * i + 1];
      float fr = expf(-(float)i * (9.210340371976184f / 32.0f));
      float sn, cs;
      sincosf((float)s * fr, &sn, &cs);
      bf16* k = Kb + ((size_t)(b * SEQ + s)) * HD + 2 * i;
      k[0] = __float2bfloat16(x1 * cs - x2 * sn);
      k[1] = __float2bfloat16(x1 * sn + x2 * cs);
    } else {                            // v -> transposed Vt[b][d][s]
      int i = t - 544;
      Vt[((size_t)(b * HD + 2 * i)) * SEQ + s]     = __float2bfloat16(y[1088 + 2 * i]);
      Vt[((size_t)(b * HD + 2 * i + 1)) * SEQ + s] = __float2bfloat16(y[1088 + 2 * i + 1]);
    }
  }
}

// ---------------- Flash attention (causal, MQA) -------------------------
// grid: B*NH*(SEQ/64) blocks; 4 waves/block; wave w owns 16 q-rows.
// kv tiles of 32. QK^T and PV via mfma 16x16x32 bf16.
__global__ __launch_bounds__(256) void attn_kernel(const bf16* __restrict__ Q,
                                                   const bf16* __restrict__ K,
                                                   const bf16* __restrict__ Vt,
                                                   float* __restrict__ O) {
  __shared__ bf16 pbuf[4][16][32];
  const int bid = blockIdx.x;
  const int qt = bid & 31;
  const int h  = (bid >> 5) & 15;
  const int b  = bid >> 9;
  const int w  = threadIdx.x >> 6, l = threadIdx.x & 63;
  const int lg = l >> 4, ln = l & 15;
  const int qrow0 = qt * 64 + w * 16;   // first q row of this wave (within S)

  // Q fragments (A operand): lane holds Q[ln][ks*32 + lg*8 .. +7]
  const bf16* qptr = Q + ((size_t)((b * NH + h) * SEQ + qrow0)) * HD;
  s16x8 aq[2];
  for (int ks = 0; ks < 2; ++ks)
    aq[ks] = *(const s16x8*)(qptr + (size_t)ln * HD + ks * 32 + lg * 8);

  f32x4 o[4] = {};
  float mrow[4] = {-1e30f, -1e30f, -1e30f, -1e30f};
  float lsum[4] = {0.f, 0.f, 0.f, 0.f};

  const bf16* kbase = K + (size_t)b * SEQ * HD;
  const bf16* vbase = Vt + (size_t)b * HD * SEQ;
  const int kv_end = qt * 64 + 64;

  for (int kvb = 0; kvb < kv_end; kvb += 32) {
    // ---- S = Q K^T (16 q x 32 kv) ----
    f32x4 s[2] = {};
    for (int nt = 0; nt < 2; ++nt)
      for (int ks = 0; ks < 2; ++ks) {
        s16x8 bk = *(const s16x8*)(kbase + (size_t)(kvb + nt * 16 + ln) * HD + ks * 32 + lg * 8);
        s[nt] = __builtin_amdgcn_mfma_f32_16x16x32_bf16(aq[ks], bk, s[nt], 0, 0, 0);
      }
    // scale + causal mask
    for (int nt = 0; nt < 2; ++nt)
      for (int r = 0; r < 4; ++r) {
        int kvg = kvb + nt * 16 + ln;
        int qg  = qrow0 + 4 * lg + r;
        float v = s[nt][r] * 0.125f;
        s[nt][r] = (kvg <= qg) ? v : -1e30f;
      }
    // row max over 32 cols (16 lanes per group x 2 tiles)
    float pm[4];
    for (int r = 0; r < 4; ++r) pm[r] = fmaxf(s[0][r], s[1][r]);
    for (int off = 1; off < 16; off <<= 1)
      for (int r = 0; r < 4; ++r) pm[r] = fmaxf(pm[r], __shfl_xor(pm[r], off));
    float alpha[4];
    for (int r = 0; r < 4; ++r) {
      float nm = fmaxf(mrow[r], pm[r]);
      alpha[r] = __expf(mrow[r] - nm);
      mrow[r] = nm;
    }
    // p = exp(s - m), row sums
    float rs[4] = {0.f, 0.f, 0.f, 0.f};
    for (int nt = 0; nt < 2; ++nt)
      for (int r = 0; r < 4; ++r) {
        float p = __expf(s[nt][r] - mrow[r]);
        s[nt][r] = p;
        rs[r] += p;
      }
    for (int off = 1; off < 16; off <<= 1)
      for (int r = 0; r < 4; ++r) rs[r] += __shfl_xor(rs[r], off);
    for (int r = 0; r < 4; ++r) lsum[r] = lsum[r] * alpha[r] + rs[r];
    for (int nt = 0; nt < 4; ++nt)
      for (int r = 0; r < 4; ++r) o[nt][r] *= alpha[r];

    // ---- transpose P via LDS: C/D layout -> A-frag layout ----
    for (int nt = 0; nt < 2; ++nt)
      for (int r = 0; r < 4; ++r)
        pbuf[w][4 * lg + r][nt * 16 + ln] = __float2bfloat16(s[nt][r]);
    __syncthreads();
    s16x8 ap = *(const s16x8*)(&pbuf[w][ln][lg * 8]);

    // ---- O += P V ----
    for (int nt = 0; nt < 4; ++nt) {
      s16x8 bv = *(const s16x8*)(vbase + (size_t)(nt * 16 + ln) * SEQ + kvb + lg * 8);
      o[nt] = __builtin_amdgcn_mfma_f32_16x16x32_bf16(ap, bv, o[nt], 0, 0, 0);
    }
    __syncthreads();
  }

  // epilogue: normalize + scatter to O[b][s][h*64+d] (fp32)
  for (int nt = 0; nt < 4; ++nt)
    for (int r = 0; r < 4; ++r) {
      int qg = qrow0 + 4 * lg + r;
      O[((size_t)(b * SEQ + qg)) * DIMC + h * HD + nt * 16 + ln] = o[nt][r] / lsum[r];
    }
}

// ---------------- RMS norm (per row of 1024) -> bf16 ----------------
__global__ __launch_bounds__(256) void rmsnorm_kernel(const float* __restrict__ X,
                                                      const float* __restrict__ wgt,
                                                      bf16* __restrict__ out) {
  const int r = blockIdx.x;
  const float* x = X + (size_t)r * DIMC;
  float4 v = ((const float4*)x)[threadIdx.x];
  float ss = v.x * v.x + v.y * v.y + v.z * v.z + v.w * v.w;
  for (int off = 32; off; off >>= 1) ss += __shfl_xor(ss, off);
  __shared__ float part[4];
  if ((threadIdx.x & 63) == 0) part[threadIdx.x >> 6] = ss;
  __syncthreads();
  float tot = part[0] + part[1] + part[2] + part[3];
  float rms = rsqrtf(tot * (1.0f / 1024.0f) + 1e-6f);
  bf16* o = out + (size_t)r * DIMC;
  int c = threadIdx.x * 4;
  o[c + 0] = __float2bfloat16((v.x * rms) * wgt[c + 0]);
  o[c + 1] = __float2bfloat16((v.y * rms) * wgt[c + 1]);
  o[c + 2] = __float2bfloat16((v.z * rms) * wgt[c + 2]);
  o[c + 3] = __float2bfloat16((v.w * rms) * wgt[c + 3]);
}

// ---------------- launch ----------------
extern "C" void kernel_launch(void* const* d_in, const int* in_sizes, int n_in,
                              void* d_out, int out_size, void* d_ws, size_t ws_size,
                              hipStream_t stream) {
  const float* x      = (const float*)d_in[0];
  const float* Wq     = (const float*)d_in[1];
  const float* Wk     = (const float*)d_in[2];
  const float* Wv     = (const float*)d_in[3];
  const float* Wo     = (const float*)d_in[4];
  const float* norm_w = (const float*)d_in[5];

  size_t off = 0;
  auto alloc = [&](size_t bytes) {
    void* p = (char*)d_ws + off;
    off += (bytes + 255) & ~(size_t)255;
    return p;
  };
  bf16*  Xbf  = (bf16*)alloc((size_t)NROWS * DIMC * 2);
  bf16*  Wqkv = (bf16*)alloc((size_t)NQKV * DIMC * 2);
  bf16*  Wob  = (bf16*)alloc((size_t)DIMC * DIMC * 2);
  float* Y    = (float*)alloc((size_t)NROWS * NQKV * 4);
  bf16*  Qb   = (bf16*)alloc((size_t)NB * NH * SEQ * HD * 2);
  bf16*  Kb   = (bf16*)alloc((size_t)NB * SEQ * HD * 2);
  bf16*  Vt   = (bf16*)alloc((size_t)NB * HD * SEQ * 2);
  float* AO   = (float*)alloc((size_t)NROWS * DIMC * 4);
  bf16*  Nb   = (bf16*)alloc((size_t)NROWS * DIMC * 2);

  auto cast = [&](const float* s, bf16* d, int n) {
    int n4 = n / 4;
    cast_kernel<<<(n4 + 255) / 256, 256, 0, stream>>>(s, d, n4);
  };
  cast(x,  Xbf, NROWS * DIMC);
  cast(Wq, Wqkv, DIMC * DIMC);
  cast(Wk, Wqkv + (size_t)1024 * 1024, HD * DIMC);
  cast(Wv, Wqkv + (size_t)1088 * 1024, HD * DIMC);
  cast(Wo, Wob, DIMC * DIMC);

  // QKV projection: Y[4096][1152] = Xbf @ Wqkv^T
  gemm_bt<<<dim3(NROWS / 128, NQKV / 128), 256, 0, stream>>>(Xbf, Wqkv, Y, NROWS, NQKV, DIMC);

  // RoPE + layout
  rope_kernel<<<NROWS, 256, 0, stream>>>(Y, Qb, Kb, Vt);

  // attention
  attn_kernel<<<NB * NH * (SEQ / 64), 256, 0, stream>>>(Qb, Kb, Vt, AO);

  // rms norm
  rmsnorm_kernel<<<NROWS, 256, 0, stream>>>(AO, norm_w, Nb);

  // output projection into d_out (fp32)
  gemm_bt<<<dim3(NROWS / 128, DIMC / 128), 256, 0, stream>>>(Nb, Wob, (float*)d_out, NROWS, DIMC, DIMC);
}

// Round 2
// 197.486 us; speedup vs baseline: 1.7141x; 1.7141x over previous
//
#include <hip/hip_runtime.h>
#include <hip/hip_bf16.h>

typedef __attribute__((ext_vector_type(4)))  float f32x4;
typedef __attribute__((ext_vector_type(16))) float f32x16;
typedef __attribute__((ext_vector_type(8)))  short s16x8;
typedef __attribute__((ext_vector_type(4)))  unsigned int u32x4;

using bf16 = __hip_bfloat16;

#define DIMC   1024
#define NH     16
#define HD     64
#define SEQ    2048
#define NB     2
#define NROWS  (NB*SEQ)   // 4096
#define NQKV   1152       // 1024 q + 64 k + 64 v

// ---------------- cast fp32 -> bf16 (4 elems/thread) ----------------
__global__ __launch_bounds__(256) void cast_kernel(const float* __restrict__ src,
                                                   bf16* __restrict__ dst, int n4) {
  int i = blockIdx.x * blockDim.x + threadIdx.x;
  if (i < n4) {
    float4 v = ((const float4*)src)[i];
    bf16* d = dst + (size_t)i * 4;
    d[0] = __float2bfloat16(v.x);
    d[1] = __float2bfloat16(v.y);
    d[2] = __float2bfloat16(v.z);
    d[3] = __float2bfloat16(v.w);
  }
}

// ---------------- bf16 GEMM: C[M][N] = A[M][K] * B[N][K]^T  (fp32 out) ----
// 128x128 tile, BK=64, 4 waves (2x2), per-wave 64x64, mfma 16x16x32 bf16.
// Staging via global_load_lds width=16 (LDS dest is base + lane*16 exactly).
__global__ __launch_bounds__(256) void gemm_bt(const bf16* __restrict__ A,
                                               const bf16* __restrict__ Bm,
                                               float* __restrict__ C,
                                               int M, int N, int K) {
  __shared__ bf16 lA[128 * 64];
  __shared__ bf16 lB[128 * 64];
  const int tid = threadIdx.x;
  const int w = tid >> 6, l = tid & 63;
  const int lg = l >> 4, ln = l & 15;
  const int wr = w >> 1, wc = w & 1;
  const int m0 = blockIdx.x * 128, n0 = blockIdx.y * 128;

  f32x4 acc[4][4] = {};

  for (int k0 = 0; k0 < K; k0 += 64) {
    // stage A and B tiles (128x64 bf16 each): 16B direct-to-LDS
#pragma unroll
    for (int it = 0; it < 4; ++it) {
      int c = tid + it * 256;
      int row = c >> 3, col = (c & 7) * 8;
      __builtin_amdgcn_global_load_lds(
          (const __attribute__((address_space(1))) void*)(A + (size_t)(m0 + row) * K + k0 + col),
          (__attribute__((address_space(3))) void*)(&lA[c * 8]), 16, 0, 0);
      __builtin_amdgcn_global_load_lds(
          (const __attribute__((address_space(1))) void*)(Bm + (size_t)(n0 + row) * K + k0 + col),
          (__attribute__((address_space(3))) void*)(&lB[c * 8]), 16, 0, 0);
    }
    __syncthreads();
    for (int ks = 0; ks < 2; ++ks) {
      s16x8 af[4], bfr[4];
      for (int m = 0; m < 4; ++m)
        af[m] = *(const s16x8*)(&lA[(wr * 64 + m * 16 + ln) * 64 + ks * 32 + lg * 8]);
      for (int n = 0; n < 4; ++n)
        bfr[n] = *(const s16x8*)(&lB[(wc * 64 + n * 16 + ln) * 64 + ks * 32 + lg * 8]);
      for (int m = 0; m < 4; ++m)
        for (int n = 0; n < 4; ++n)
          acc[m][n] = __builtin_amdgcn_mfma_f32_16x16x32_bf16(af[m], bfr[n], acc[m][n], 0, 0, 0);
    }
    __syncthreads();
  }

  for (int m = 0; m < 4; ++m)
    for (int n = 0; n < 4; ++n)
      for (int r = 0; r < 4; ++r)
        C[(size_t)(m0 + wr * 64 + m * 16 + lg * 4 + r) * N + n0 + wc * 64 + n * 16 + ln] =
            acc[m][n][r];
}

// ---------------- RoPE + layout: Y[4096][1152] fp32 -> Q,K (rotated bf16), Vt ----
__global__ __launch_bounds__(256) void rope_kernel(const float* __restrict__ Y,
                                                   bf16* __restrict__ Qb,
                                                   bf16* __restrict__ Kb,
                                                   bf16* __restrict__ Vt) {
  const int r = blockIdx.x;             // 0..4095
  const int b = r >> 11, s = r & 2047;
  const float* y = Y + (size_t)r * NQKV;
  for (int t = threadIdx.x; t < 576; t += blockDim.x) {
    if (t < 512) {                      // q pairs: h = t/32, i = t%32
      int h = t >> 5, i = t & 31;
      float x1 = y[h * 64 + 2 * i], x2 = y[h * 64 + 2 * i + 1];
      float fr = expf(-(float)i * (9.210340371976184f / 32.0f)); // theta^(-i/32)
      float sn, cs;
      sincosf((float)s * fr, &sn, &cs);
      bf16* q = Qb + ((size_t)((b * NH + h) * SEQ + s)) * HD + 2 * i;
      q[0] = __float2bfloat16(x1 * cs - x2 * sn);
      q[1] = __float2bfloat16(x1 * sn + x2 * cs);
    } else if (t < 544) {               // k pairs
      int i = t - 512;
      float x1 = y[1024 + 2 * i], x2 = y[1024 + 2 * i + 1];
      float fr = expf(-(float)i * (9.210340371976184f / 32.0f));
      float sn, cs;
      sincosf((float)s * fr, &sn, &cs);
      bf16* k = Kb + ((size_t)(b * SEQ + s)) * HD + 2 * i;
      k[0] = __float2bfloat16(x1 * cs - x2 * sn);
      k[1] = __float2bfloat16(x1 * sn + x2 * cs);
    } else {                            // v -> transposed Vt[b][d][s]
      int i = t - 544;
      Vt[((size_t)(b * HD + 2 * i)) * SEQ + s]     = __float2bfloat16(y[1088 + 2 * i]);
      Vt[((size_t)(b * HD + 2 * i + 1)) * SEQ + s] = __float2bfloat16(y[1088 + 2 * i + 1]);
    }
  }
}

// ---- cross-lane helpers (gfx950) ----
static __device__ __forceinline__ unsigned cvt_pk_bf16(float lo, float hi) {
  unsigned r;
  asm("v_cvt_pk_bf16_f32 %0, %1, %2" : "=v"(r) : "v"(lo), "v"(hi));
  return r;
}
static __device__ __forceinline__ void pl32_swap(unsigned& x, unsigned& y) {
  asm("v_permlane32_swap_b32 %0, %1" : "+v"(x), "+v"(y));
}

// ---------------- Flash attention v2 (causal, MQA) -------------------------
// grid: B*NH*(SEQ/128) = 512 blocks, 4 waves; wave w owns 32 q rows.
// Swapped QK^T with 32x32x16 MFMA: lane owns q-col = lane&31; S^T rows
// (kv) = (r&3)+8*(r>>2)+4*(lane>>5). Softmax in-register; P -> B-frag via
// cvt_pk_bf16 + permlane32_swap. PV: O^T = mfma(V^T, P^T). No LDS, no barriers.
__global__ __launch_bounds__(256) void attn2_kernel(const bf16* __restrict__ Q,
                                                    const bf16* __restrict__ K,
                                                    const bf16* __restrict__ Vt,
                                                    float* __restrict__ O) {
  const int bid = blockIdx.x;
  const int qt = bid & 15;
  const int h  = (bid >> 4) & 15;
  const int b  = bid >> 8;
  const int w  = threadIdx.x >> 6, l = threadIdx.x & 63;
  const int ql = l & 31, hi = l >> 5;
  const int qb0 = qt * 128 + w * 32;
  const int qg  = qb0 + ql;             // this lane's q row

  // Q B-fragments (hoisted): chunk ks: Q[qg][ks*16 + hi*8 + j], j=0..7
  const bf16* qrow = Q + ((size_t)((b * NH + h) * SEQ + qg)) * HD;
  s16x8 qf[4];
#pragma unroll
  for (int ks = 0; ks < 4; ++ks)
    qf[ks] = *(const s16x8*)(qrow + ks * 16 + hi * 8);

  const bf16* kbase = K + (size_t)b * SEQ * HD;
  const bf16* vbase = Vt + (size_t)b * HD * SEQ;

  f32x16 ot[2] = {};                    // O^T accum: [d-tile 0/1], C layout
  float m2 = -1e30f, ls = 0.f;          // running max (log2 domain), sum

  const float SCL = 0.125f * 1.44269504f;   // 1/sqrt(64) * log2(e)
  // precompute this lane's S^T kv-row offsets
  int crow[16];
#pragma unroll
  for (int r = 0; r < 16; ++r) crow[r] = (r & 3) + 8 * (r >> 2) + 4 * hi;

  auto tile = [&](int kvb, bool diag) {
    // ---- S^T = K_tile @ Q_tile^T  (32 kv x 32 q) ----
    f32x16 st = {};
#pragma unroll
    for (int ks = 0; ks < 4; ++ks) {
      s16x8 kf = *(const s16x8*)(kbase + (size_t)(kvb + ql) * HD + ks * 16 + hi * 8);
      st = __builtin_amdgcn_mfma_f32_32x32x16_bf16(kf, qf[ks], st, 0, 0, 0);
    }
    // scale (+ mask on diagonal tile only)
    float p[16];
#pragma unroll
    for (int r = 0; r < 16; ++r) {
      float v = st[r] * SCL;
      p[r] = (diag && crow[r] > ql) ? -1e30f : v;
    }
    // row max: in-lane tree + one cross-half exchange
    float t[8];
#pragma unroll
    for (int r = 0; r < 8; ++r) t[r] = fmaxf(p[2 * r], p[2 * r + 1]);
#pragma unroll
    for (int r = 0; r < 4; ++r) t[r] = fmaxf(t[r], t[r + 4]);
    t[0] = fmaxf(t[0], t[2]); t[1] = fmaxf(t[1], t[3]);
    float pm = fmaxf(t[0], t[1]);
    pm = fmaxf(pm, __shfl_xor(pm, 32));
    // online-softmax update
    float nm = fmaxf(m2, pm);
    float alpha = exp2f(m2 - nm);
    m2 = nm;
#pragma unroll
    for (int r = 0; r < 16; ++r) p[r] = exp2f(p[r] - m2);
#pragma unroll
    for (int r = 0; r < 8; ++r) t[r] = p[2 * r] + p[2 * r + 1];
#pragma unroll
    for (int r = 0; r < 4; ++r) t[r] = t[r] + t[r + 4];
    float rs = (t[0] + t[2]) + (t[1] + t[3]);
    rs += __shfl_xor(rs, 32);
    ls = ls * alpha + rs;
#pragma unroll
    for (int dt = 0; dt < 2; ++dt)
#pragma unroll
      for (int r = 0; r < 16; ++r) ot[dt][r] *= alpha;

    // ---- P^T -> B-frag (per 16-kv chunk) + PV ----
#pragma unroll
    for (int c = 0; c < 2; ++c) {
      unsigned w0 = cvt_pk_bf16(p[c * 8 + 0], p[c * 8 + 1]);
      unsigned w2 = cvt_pk_bf16(p[c * 8 + 4], p[c * 8 + 5]);
      unsigned w1 = cvt_pk_bf16(p[c * 8 + 2], p[c * 8 + 3]);
      unsigned w3 = cvt_pk_bf16(p[c * 8 + 6], p[c * 8 + 7]);
      pl32_swap(w0, w2);   // -> word0 (j0,j1), word2 (j4,j5)
      pl32_swap(w1, w3);   // -> word1 (j2,j3), word3 (j6,j7)
      u32x4 pu = {w0, w1, w2, w3};
      s16x8 pb = *(s16x8*)&pu;
#pragma unroll
      for (int dt = 0; dt < 2; ++dt) {
        s16x8 vf = *(const s16x8*)(vbase + (size_t)(dt * 32 + ql) * SEQ + kvb + c * 16 + hi * 8);
        ot[dt] = __builtin_amdgcn_mfma_f32_32x32x16_bf16(vf, pb, ot[dt], 0, 0, 0);
      }
    }
  };

  for (int kvb = 0; kvb < qb0; kvb += 32) tile(kvb, false);
  tile(qb0, true);

  // epilogue: O[qg][d] = ot / ls   (d = dt*32 + 8*rq + 4*hi + j)
  float inv = 1.0f / ls;
  float* obase = O + (size_t)(b * SEQ + qg) * DIMC + h * HD;
#pragma unroll
  for (int dt = 0; dt < 2; ++dt)
#pragma unroll
    for (int rq = 0; rq < 4; ++rq) {
      float4 v = { ot[dt][4 * rq + 0] * inv, ot[dt][4 * rq + 1] * inv,
                   ot[dt][4 * rq + 2] * inv, ot[dt][4 * rq + 3] * inv };
      *(float4*)(obase + dt * 32 + rq * 8 + 4 * hi) = v;
    }
}

// ---------------- RMS norm (per row of 1024) -> bf16 ----------------
__global__ __launch_bounds__(256) void rmsnorm_kernel(const float* __restrict__ X,
                                                      const float* __restrict__ wgt,
                                                      bf16* __restrict__ out) {
  const int r = blockIdx.x;
  const float* x = X + (size_t)r * DIMC;
  float4 v = ((const float4*)x)[threadIdx.x];
  float ss = v.x * v.x + v.y * v.y + v.z * v.z + v.w * v.w;
  for (int off = 32; off; off >>= 1) ss += __shfl_xor(ss, off);
  __shared__ float part[4];
  if ((threadIdx.x & 63) == 0) part[threadIdx.x >> 6] = ss;
  __syncthreads();
  float tot = part[0] + part[1] + part[2] + part[3];
  float rms = rsqrtf(tot * (1.0f / 1024.0f) + 1e-6f);
  bf16* o = out + (size_t)r * DIMC;
  int c = threadIdx.x * 4;
  o[c + 0] = __float2bfloat16((v.x * rms) * wgt[c + 0]);
  o[c + 1] = __float2bfloat16((v.y * rms) * wgt[c + 1]);
  o[c + 2] = __float2bfloat16((v.z * rms) * wgt[c + 2]);
  o[c + 3] = __float2bfloat16((v.w * rms) * wgt[c + 3]);
}

// ---------------- launch ----------------
extern "C" void kernel_launch(void* const* d_in, const int* in_sizes, int n_in,
                              void* d_out, int out_size, void* d_ws, size_t ws_size,
                              hipStream_t stream) {
  const float* x      = (const float*)d_in[0];
  const float* Wq     = (const float*)d_in[1];
  const float* Wk     = (const float*)d_in[2];
  const float* Wv     = (const float*)d_in[3];
  const float* Wo     = (const float*)d_in[4];
  const float* norm_w = (const float*)d_in[5];

  size_t off = 0;
  auto alloc = [&](size_t bytes) {
    void* p = (char*)d_ws + off;
    off += (bytes + 255) & ~(size_t)255;
    return p;
  };
  bf16*  Xbf  = (bf16*)alloc((size_t)NROWS * DIMC * 2);
  bf16*  Wqkv = (bf16*)alloc((size_t)NQKV * DIMC * 2);
  bf16*  Wob  = (bf16*)alloc((size_t)DIMC * DIMC * 2);
  float* Y    = (float*)alloc((size_t)NROWS * NQKV * 4);
  bf16*  Qb   = (bf16*)alloc((size_t)NB * NH * SEQ * HD * 2);
  bf16*  Kb   = (bf16*)alloc((size_t)NB * SEQ * HD * 2);
  bf16*  Vt   = (bf16*)alloc((size_t)NB * HD * SEQ * 2);
  float* AO   = (float*)alloc((size_t)NROWS * DIMC * 4);
  bf16*  Nb   = (bf16*)alloc((size_t)NROWS * DIMC * 2);

  auto cast = [&](const float* s, bf16* d, int n) {
    int n4 = n / 4;
    cast_kernel<<<(n4 + 255) / 256, 256, 0, stream>>>(s, d, n4);
  };
  cast(x,  Xbf, NROWS * DIMC);
  cast(Wq, Wqkv, DIMC * DIMC);
  cast(Wk, Wqkv + (size_t)1024 * 1024, HD * DIMC);
  cast(Wv, Wqkv + (size_t)1088 * 1024, HD * DIMC);
  cast(Wo, Wob, DIMC * DIMC);

  // QKV projection: Y[4096][1152] = Xbf @ Wqkv^T
  gemm_bt<<<dim3(NROWS / 128, NQKV / 128), 256, 0, stream>>>(Xbf, Wqkv, Y, NROWS, NQKV, DIMC);

  // RoPE + layout
  rope_kernel<<<NROWS, 256, 0, stream>>>(Y, Qb, Kb, Vt);

  // attention v2
  attn2_kernel<<<NB * NH * (SEQ / 128), 256, 0, stream>>>(Qb, Kb, Vt, AO);

  // rms norm
  rmsnorm_kernel<<<NROWS, 256, 0, stream>>>(AO, norm_w, Nb);

  // output projection into d_out (fp32)
  gemm_bt<<<dim3(NROWS / 128, DIMC / 128), 256, 0, stream>>>(Nb, Wob, (float*)d_out, NROWS, DIMC, DIMC);
}